// Round 1
// baseline (307.883 us; speedup 1.0000x reference)
//
#include <hip/hip_runtime.h>
#include <hip/hip_bf16.h>
#include <cstdint>

typedef __bf16 bf16;
typedef __bf16 bf16x8 __attribute__((ext_vector_type(8)));
typedef __bf16 bf16x4 __attribute__((ext_vector_type(4)));
typedef float f32x4 __attribute__((ext_vector_type(4)));

__device__ __forceinline__ void gld_lds16(const void* g, void* l) {
  __builtin_amdgcn_global_load_lds((const __attribute__((address_space(1))) void*)g,
                                   (__attribute__((address_space(3))) void*)l, 16, 0, 0);
}

enum { BIAS_NONE = 0, BIAS_COL = 1, BIAS_ROW = 2 };
enum { OUT_BF16 = 0, OUT_F32_RESID = 1 };

// C[M,N] = A[M,K] * B^T (B stored [N,K], K contiguous) ; 128x128 tile, 4 waves.
// LDS tiles logical [128 rows][64 k] bf16 (128B rows), swizzle: byte bits[6:4] ^= row&7,
// applied via inverse-swizzled global_load_lds source + swizzled ds_read addresses.
template<int BIAS_MODE, int OUT_MODE>
__global__ __launch_bounds__(256)
void gemm_bt(const bf16* __restrict__ A, long sA, int lda,
             const bf16* __restrict__ Bm, long sB, int ldb,
             void* __restrict__ Cv, long sC, int ldc,
             const float* __restrict__ bias,
             const float* __restrict__ resid, long sR,
             int K, float scale)
{
  const int bm = blockIdx.x, bn = blockIdx.y, bz = blockIdx.z;
  const char* Ab = (const char*)(A + (long)bz * sA);
  const char* Bb = (const char*)(Bm + (long)bz * sB);
  const int tid = threadIdx.x;
  const int wave = tid >> 6, lane = tid & 63;
  const int wr = wave >> 1, wc = wave & 1;

  __shared__ __attribute__((aligned(128))) char lds[32768];
  char* ldsA = lds;
  char* ldsB = lds + 16384;

  // fragment ds_read byte offsets (physical, swizzled); kk=1 flips bit 6
  uint32_t aoff[4], boff[4];
#pragma unroll
  for (int i = 0; i < 4; ++i) {
    uint32_t ra = (uint32_t)(wr * 64 + i * 16 + (lane & 15));
    uint32_t la = ra * 128u + (uint32_t)((lane >> 4) << 4);
    aoff[i] = la ^ ((la >> 3) & 0x70u);
    uint32_t rb = (uint32_t)(wc * 64 + i * 16 + (lane & 15));
    uint32_t lb = rb * 128u + (uint32_t)((lane >> 4) << 4);
    boff[i] = lb ^ ((lb >> 3) & 0x70u);
  }

  // staging: physical slot -> logical (row, in-row byte) via same involution
  uint32_t srow[4], sinb[4];
#pragma unroll
  for (int t = 0; t < 4; ++t) {
    uint32_t paddr = (uint32_t)(((wave * 4 + t) * 64 + lane) * 16);
    uint32_t laddr = paddr ^ ((paddr >> 3) & 0x70u);
    srow[t] = laddr >> 7;
    sinb[t] = laddr & 127u;
  }

  const long ldab = (long)lda * 2, ldbb = (long)ldb * 2;
  const long arow0 = (long)bm * 128, brow0 = (long)bn * 128;

  f32x4 acc[4][4] = {};

  const int nK = K >> 6;
  for (int kt = 0; kt < nK; ++kt) {
    const long k0b = (long)kt * 128;
#pragma unroll
    for (int t = 0; t < 4; ++t) {
      gld_lds16(Ab + (arow0 + srow[t]) * ldab + k0b + sinb[t],
                ldsA + (wave * 4 + t) * 1024);
      gld_lds16(Bb + (brow0 + srow[t]) * ldbb + k0b + sinb[t],
                ldsB + (wave * 4 + t) * 1024);
    }
    __syncthreads();
#pragma unroll
    for (int kk = 0; kk < 2; ++kk) {
      bf16x8 af[4], bfr[4];
#pragma unroll
      for (int i = 0; i < 4; ++i) {
        af[i]  = *(const bf16x8*)(ldsA + (aoff[i] ^ (kk << 6)));
        bfr[i] = *(const bf16x8*)(ldsB + (boff[i] ^ (kk << 6)));
      }
#pragma unroll
      for (int mi = 0; mi < 4; ++mi)
#pragma unroll
        for (int ni = 0; ni < 4; ++ni)
          acc[mi][ni] = __builtin_amdgcn_mfma_f32_16x16x32_bf16(af[mi], bfr[ni], acc[mi][ni], 0, 0, 0);
    }
    __syncthreads();
  }

  const int cl = lane & 15, rq = lane >> 4;
  const long row0 = (long)bm * 128 + wr * 64;
  const long col0 = (long)bn * 128 + wc * 64;

  if constexpr (OUT_MODE == OUT_BF16) {
    bf16* Co = (bf16*)Cv + (long)bz * sC;
#pragma unroll
    for (int mi = 0; mi < 4; ++mi) {
#pragma unroll
      for (int ni = 0; ni < 4; ++ni) {
        const long col = col0 + ni * 16 + cl;
        float bc = 0.f;
        if (BIAS_MODE == BIAS_COL) bc = bias[col];
#pragma unroll
        for (int j = 0; j < 4; ++j) {
          const long row = row0 + mi * 16 + rq * 4 + j;
          float v = acc[mi][ni][j] * scale + bc;
          if (BIAS_MODE == BIAS_ROW) v += bias[row];
          Co[row * ldc + col] = (bf16)v;
        }
      }
    }
  } else {
    float* Co = (float*)Cv + (long)bz * sC;
    const float* X = resid + (long)bz * sR;
#pragma unroll
    for (int mi = 0; mi < 4; ++mi) {
#pragma unroll
      for (int ni = 0; ni < 4; ++ni) {
        const long col = col0 + ni * 16 + cl;
#pragma unroll
        for (int j = 0; j < 4; ++j) {
          const long row = row0 + mi * 16 + rq * 4 + j;
          Co[row * ldc + col] = acc[mi][ni][j] + bias[row] + X[row * ldc + col];
        }
      }
    }
  }
}

// per-(batch,group) mean/rstd over contiguous 16*4096 floats
__global__ __launch_bounds__(256)
void gn_stats(const float* __restrict__ x, float* __restrict__ stats)
{
  const int bg = blockIdx.x;
  const float4* px = (const float4*)(x + (long)bg * 65536);
  float s1 = 0.f, s2 = 0.f;
  for (int i = threadIdx.x; i < 16384; i += 256) {
    float4 f = px[i];
    s1 += f.x + f.y + f.z + f.w;
    s2 += f.x * f.x + f.y * f.y + f.z * f.z + f.w * f.w;
  }
#pragma unroll
  for (int d = 32; d > 0; d >>= 1) {
    s1 += __shfl_xor(s1, d, 64);
    s2 += __shfl_xor(s2, d, 64);
  }
  __shared__ float r1[4], r2[4];
  const int wave = threadIdx.x >> 6, lane = threadIdx.x & 63;
  if (lane == 0) { r1[wave] = s1; r2[wave] = s2; }
  __syncthreads();
  if (threadIdx.x == 0) {
    float t1 = r1[0] + r1[1] + r1[2] + r1[3];
    float t2 = r2[0] + r2[1] + r2[2] + r2[3];
    float mean = t1 * (1.f / 65536.f);
    float var  = t2 * (1.f / 65536.f) - mean * mean;
    stats[bg * 2]     = mean;
    stats[bg * 2 + 1] = rsqrtf(var + 1e-6f);
  }
}

// normalize x[b,c,n] and transpose to hn[b,n,c] bf16 via LDS (64 n x 512 c tile).
// LDS swizzle at 16B granularity: byte bits[6:4] ^= (row>>2)&7 (row = local n).
__global__ __launch_bounds__(256)
void gn_apply(const float* __restrict__ x, const float* __restrict__ stats,
              const float* __restrict__ gamma, const float* __restrict__ beta,
              bf16* __restrict__ hn)
{
  const int b = blockIdx.y;
  const int n0 = blockIdx.x * 64;
  __shared__ __attribute__((aligned(16))) char lt[65536]; // [64][512] bf16 swizzled
  const int tid = threadIdx.x;

  for (int i = 0; i < 32; ++i) {
    int f = i * 256 + tid;       // 0..8191
    int c = f >> 4;              // 0..511
    int n4 = f & 15;             // float4 index along n
    float4 xv = *(const float4*)(x + (((long)b * 512 + c) * 4096) + n0 + n4 * 4);
    int g = c >> 4;
    float mean = stats[(b * 32 + g) * 2];
    float rstd = stats[(b * 32 + g) * 2 + 1];
    float ga = gamma[c], be = beta[c];
    float y[4];
    y[0] = (xv.x - mean) * rstd * ga + be;
    y[1] = (xv.y - mean) * rstd * ga + be;
    y[2] = (xv.z - mean) * rstd * ga + be;
    y[3] = (xv.w - mean) * rstd * ga + be;
    uint32_t cb = (uint32_t)(c * 2);
#pragma unroll
    for (int jj = 0; jj < 4; ++jj) {
      uint32_t nl = (uint32_t)(n4 * 4 + jj);
      uint32_t phys = nl * 1024u + (cb ^ (((nl >> 2) & 7u) << 4));
      *(bf16*)(lt + phys) = (bf16)y[jj];
    }
  }
  __syncthreads();
  for (int i = 0; i < 16; ++i) {
    int j = i * 256 + tid;       // 16B chunk id, 0..4095
    uint32_t row = (uint32_t)(j >> 6);
    uint32_t m = (uint32_t)(j & 63);
    uint32_t phys = row * 1024u + ((m * 16u) ^ (((row >> 2) & 7u) << 4));
    uint4 val = *(const uint4*)(lt + phys);
    *(uint4*)((char*)(hn + ((long)b * 4096 + n0 + row) * 512) + m * 16) = val;
  }
}

__global__ __launch_bounds__(256)
void f32_to_bf16_k(const float* __restrict__ src, bf16* __restrict__ dst, int n4)
{
  int i = blockIdx.x * 256 + threadIdx.x;
  if (i < n4) {
    float4 f = ((const float4*)src)[i];
    bf16x4 o;
    o[0] = (bf16)f.x; o[1] = (bf16)f.y; o[2] = (bf16)f.z; o[3] = (bf16)f.w;
    ((bf16x4*)dst)[i] = o;
  }
}

// one wave per row of 4096 bf16; fp32 math in registers; in-place
__global__ __launch_bounds__(256)
void softmax_rows(bf16* __restrict__ S)
{
  const long row = (long)blockIdx.x * 4 + (threadIdx.x >> 6);
  const int lane = threadIdx.x & 63;
  bf16* p = S + row * 4096;
  float v[64];
#pragma unroll
  for (int i = 0; i < 8; ++i) {
    bf16x8 c = *(const bf16x8*)(p + (i * 64 + lane) * 8);
#pragma unroll
    for (int j = 0; j < 8; ++j) v[i * 8 + j] = (float)c[j];
  }
  float m = -3.0e38f;
#pragma unroll
  for (int i = 0; i < 64; ++i) m = fmaxf(m, v[i]);
#pragma unroll
  for (int d = 32; d > 0; d >>= 1) m = fmaxf(m, __shfl_xor(m, d, 64));
  float s = 0.f;
#pragma unroll
  for (int i = 0; i < 64; ++i) { v[i] = __expf(v[i] - m); s += v[i]; }
#pragma unroll
  for (int d = 32; d > 0; d >>= 1) s += __shfl_xor(s, d, 64);
  const float r = 1.f / s;
#pragma unroll
  for (int i = 0; i < 8; ++i) {
    bf16x8 c;
#pragma unroll
    for (int j = 0; j < 8; ++j) c[j] = (bf16)(v[i * 8 + j] * r);
    *(bf16x8*)(p + (i * 64 + lane) * 8) = c;
  }
}

extern "C" void kernel_launch(void* const* d_in, const int* in_sizes, int n_in,
                              void* d_out, int out_size, void* d_ws, size_t ws_size,
                              hipStream_t stream)
{
  const float* x     = (const float*)d_in[0];
  const float* gamma = (const float*)d_in[1];
  const float* beta  = (const float*)d_in[2];
  const float* wq = (const float*)d_in[3];
  const float* bq = (const float*)d_in[4];
  const float* wk = (const float*)d_in[5];
  const float* bk = (const float*)d_in[6];
  const float* wv = (const float*)d_in[7];
  const float* bv = (const float*)d_in[8];
  const float* wo = (const float*)d_in[9];
  const float* bo = (const float*)d_in[10];
  float* out = (float*)d_out;

  char* ws = (char*)d_ws;
  bf16* hn  = (bf16*)(ws + 0);          // [4][4096][512]
  bf16* q   = (bf16*)(ws + 16777216);   // [4][4096][512]
  bf16* k   = (bf16*)(ws + 33554432);   // [4][4096][512]  (= K^T per batch)
  bf16* v   = (bf16*)(ws + 50331648);   // [4][512][4096]
  bf16* O   = (bf16*)(ws + 67108864);   // [4][4096][512]
  bf16* wqb = (bf16*)(ws + 83886080);
  bf16* wkb = (bf16*)(ws + 84410368);
  bf16* wvb = (bf16*)(ws + 84934656);
  bf16* wob = (bf16*)(ws + 85458944);
  float* stats = (float*)(ws + 85983232);
  bf16* S   = (bf16*)(ws + 85984256);   // tier1: [4][4096][4096], tier2: [4096][4096]

  const long sBC = 2097152;   // per-batch stride of [4096,512] / [512,4096]
  const long sS1 = 16777216;  // per-batch stride of S
  const float scale = 0.044194173824159216f; // 512^-0.5

  f32_to_bf16_k<<<256, 256, 0, stream>>>(wq, wqb, 65536);
  f32_to_bf16_k<<<256, 256, 0, stream>>>(wk, wkb, 65536);
  f32_to_bf16_k<<<256, 256, 0, stream>>>(wv, wvb, 65536);
  f32_to_bf16_k<<<256, 256, 0, stream>>>(wo, wob, 65536);
  gn_stats<<<128, 256, 0, stream>>>(x, stats);
  gn_apply<<<dim3(64, 4), 256, 0, stream>>>(x, stats, gamma, beta, hn);

  // q[b,n,o] = hn[b,n,:] . wq[o,:] + bq[o]
  gemm_bt<BIAS_COL, OUT_BF16><<<dim3(32, 4, 4), 256, 0, stream>>>(
      hn, sBC, 512, wqb, 0, 512, q, sBC, 512, bq, nullptr, 0, 512, 1.f);
  // k[b,m,o] = hn[b,m,:] . wk[o,:] + bk[o]
  gemm_bt<BIAS_COL, OUT_BF16><<<dim3(32, 4, 4), 256, 0, stream>>>(
      hn, sBC, 512, wkb, 0, 512, k, sBC, 512, bk, nullptr, 0, 512, 1.f);
  // v[b,o,m] = wv[o,:] . hn[b,m,:] + bv[o]
  gemm_bt<BIAS_ROW, OUT_BF16><<<dim3(4, 32, 4), 256, 0, stream>>>(
      wvb, 0, 512, hn, sBC, 512, v, sBC, 4096, bv, nullptr, 0, 512, 1.f);

  const bool tier1 = ws_size >= (size_t)220201984;
  if (tier1) {
    gemm_bt<BIAS_NONE, OUT_BF16><<<dim3(32, 32, 4), 256, 0, stream>>>(
        q, sBC, 512, k, sBC, 512, S, sS1, 4096, nullptr, nullptr, 0, 512, scale);
    softmax_rows<<<4096, 256, 0, stream>>>(S);
    gemm_bt<BIAS_NONE, OUT_BF16><<<dim3(32, 4, 4), 256, 0, stream>>>(
        S, sS1, 4096, v, sBC, 4096, O, sBC, 512, nullptr, nullptr, 0, 4096, 1.f);
  } else {
    for (int b = 0; b < 4; ++b) {
      gemm_bt<BIAS_NONE, OUT_BF16><<<dim3(32, 32, 1), 256, 0, stream>>>(
          q + b * sBC, 0, 512, k + b * sBC, 0, 512, S, 0, 4096, nullptr, nullptr, 0, 512, scale);
      softmax_rows<<<1024, 256, 0, stream>>>(S);
      gemm_bt<BIAS_NONE, OUT_BF16><<<dim3(32, 4, 1), 256, 0, stream>>>(
          S, 0, 4096, v + b * sBC, 0, 4096, O + b * sBC, 0, 512, nullptr, nullptr, 0, 4096, 1.f);
    }
  }

  // out[b,o,n] = wo[o,:] . O[b,n,:] + bo[o] + x[b,o,n]
  gemm_bt<BIAS_ROW, OUT_F32_RESID><<<dim3(4, 32, 4), 256, 0, stream>>>(
      wob, 0, 512, O, sBC, 512, out, sBC, 4096, bo, x, sBC, 512, 1.f);
}